// Round 7
// baseline (194.668 us; speedup 1.0000x reference)
//
#include <hip/hip_runtime.h>
#include <hip/hip_bf16.h>

typedef _Float16  f16x8  __attribute__((ext_vector_type(8)));
typedef float     f32x4  __attribute__((ext_vector_type(4)));
typedef unsigned short u16;
typedef u16       u16x4  __attribute__((ext_vector_type(4)));

__device__ __forceinline__ u16 f2h_bits(float f) {
    union { _Float16 h; u16 u; } v; v.h = (_Float16)f; return v.u;
}

template<int N> __device__ __forceinline__ void vmwait() {
    if constexpr (N == 0)      asm volatile("s_waitcnt vmcnt(0)" ::: "memory");
    else if constexpr (N == 3) asm volatile("s_waitcnt vmcnt(3)" ::: "memory");
    else if constexpr (N == 4) asm volatile("s_waitcnt vmcnt(4)" ::: "memory");
}
__device__ __forceinline__ void pipe_barrier() {
    __builtin_amdgcn_s_barrier();
    __builtin_amdgcn_sched_barrier(0);
}

// ALL fp32->fp16 conversions (x + 5 weights) + bias concat in ONE dispatch.
__global__ __launch_bounds__(256)
void cvt_all(const float* __restrict__ x,
             const float* __restrict__ Wq, const float* __restrict__ Wk,
             const float* __restrict__ Wv, const float* __restrict__ W1,
             const float* __restrict__ W2, const float* __restrict__ bq,
             const float* __restrict__ bk,
             u16* __restrict__ x16, u16* __restrict__ Wqk16, u16* __restrict__ Wv16,
             u16* __restrict__ W116, u16* __restrict__ W216, float* __restrict__ bqk) {
    const int i = blockIdx.x * 256 + threadIdx.x;
    constexpr int X4 = 8192 * 512 / 4;           // 1048576
    constexpr int S = 512 * 512 / 4, L = 2048 * 512 / 4;
    const float* src; u16* dst; int j;
    if      (i < X4)                { src = x;  dst = x16;           j = i;                }
    else if (i < X4 + S)            { src = Wq; dst = Wqk16;         j = i - X4;           }
    else if (i < X4 + 2 * S)        { src = Wk; dst = Wqk16 + 4 * S; j = i - X4 - S;       }
    else if (i < X4 + 3 * S)        { src = Wv; dst = Wv16;          j = i - X4 - 2 * S;   }
    else if (i < X4 + 3 * S + L)    { src = W1; dst = W116;          j = i - X4 - 3 * S;   }
    else if (i < X4 + 3 * S + 2 * L){ src = W2; dst = W216;          j = i - X4 - 3 * S - L; }
    else if (i < X4 + 3 * S + 2 * L + 256) {
        const int g = (i - X4 - 3 * S - 2 * L) * 4;
#pragma unroll
        for (int t = 0; t < 4; ++t) bqk[g + t] = (g + t < 512) ? bq[g + t] : bk[g + t - 512];
        return;
    } else return;
    f32x4 v = ((const f32x4*)src)[j];
    u16x4 h;
#pragma unroll
    for (int t = 0; t < 4; ++t) h[t] = f2h_bits(v[t]);
    ((u16x4*)dst)[j] = h;
}

// Stage a ROWSx32 16-bit tile (row-major, ld elems) into linear LDS [ROWS][32] via
// global_load_lds dwordx4. 4 waves (wl in 0..3) cooperate. ROWS/64 loads per thread.
template<int ROWS>
__device__ __forceinline__ void stage_rows(const u16* __restrict__ g0, int ld, u16* lds, int wl) {
    const int l = threadIdx.x & 63;
    constexpr int CH = ROWS / 64;
#pragma unroll
    for (int i = 0; i < CH; ++i) {
        const int base = (wl * CH + i) << 10;    // wave-uniform byte offset in tile
        const int off  = base + (l << 4);
        const int row  = off >> 6;               // 64 B per row (32 elems)
        const int cb   = off & 63;
        const u16* g = g0 + (size_t)row * ld + (cb >> 1);
        __builtin_amdgcn_global_load_lds((const __attribute__((address_space(1))) void*)g,
                                         (__attribute__((address_space(3))) void*)((char*)lds + base),
                                         16, 0, 0);
    }
}

// C[M,N] = A[M,K] @ B[N,K]^T (+bias). fp16 operands, fp32 accumulate.
// 3-slot LDS pipeline with counted vmcnt: at step t, stage tile t+2, compute tile t,
// then s_waitcnt vmcnt(LPT) + raw s_barrier => tile t+1 resident, t+2 still in flight.
// SPLITK=2: 512 threads; waves 0-3 do K/2 low, 4-7 high (own slots), LDS-reduce.
// OMODE: 0 = fp32 out, 2 = fp16 out, 3 = transposed-V fp16 out [4][512][2048].
template<int BN, int SPLITK, bool RELU, int OMODE, typename TC>
__global__ __launch_bounds__(256 * SPLITK, (SPLITK == 2) ? 4 : (BN == 128 ? 3 : 4))
void gemm16(const u16* __restrict__ Ag, const u16* __restrict__ Bg,
            const float* __restrict__ bias, TC* __restrict__ C,
            int K, int lda, int ldb, int ldc,
            long sA, long sB, long sC)
{
    // XCD-aware bijective swizzle (all grids have nwg % 8 == 0).
    const int nx = gridDim.x, ny = gridDim.y;
    const int nwg = nx * ny * gridDim.z;
    int bid = blockIdx.x + nx * (blockIdx.y + ny * blockIdx.z);
    int swz = (bid & 7) * (nwg >> 3) + (bid >> 3);
    const int n0 = (swz % nx) * BN; swz /= nx;
    const int m0 = (swz % ny) * 128;
    const int bz = swz / ny;

    constexpr int FR = (BN == 128) ? 4 : 2;      // 16-row A-fragments per wave
    constexpr int ATILE = 128 * 32;
    constexpr int BTILE = BN * 32;
    constexpr int BUFSZ = ATILE + BTILE;
    constexpr int LPT = 2 + BN / 64;             // gloads per thread per tile
    __shared__ __align__(16) u16 smem[SPLITK * 3 * BUFSZ];

    const int l  = threadIdx.x & 63, w = threadIdx.x >> 6;
    const int kw = (SPLITK == 2) ? (w >> 2) : 0; // k-half id
    const int wl = w & 3;                        // wave id within half
    const int wr = (BN == 128) ? (wl >> 1) * 64 : wl * 32;
    const int wc = (BN == 128) ? (wl & 1) * 64 : 0;
    const int lr = l & 15, kg = l >> 4;

    const int Kh = K / SPLITK;
    const int kb = kw * Kh;
    const int T  = Kh >> 5;                      // K-steps of 32

    const u16* Ab = Ag + (size_t)bz * sA + (size_t)m0 * lda + kb;
    const u16* Bb = Bg + (size_t)bz * sB + (size_t)n0 * ldb + kb;
    C += (size_t)bz * sC;

    u16* mybuf = smem + kw * 3 * BUFSZ;

    auto stage = [&](int slot, int t) {
        u16* s = mybuf + slot * BUFSZ;
        stage_rows<128>(Ab + t * 32, lda, s, wl);
        stage_rows<BN>(Bb + t * 32, ldb, s + ATILE, wl);
    };

    f32x4 acc[FR][4] = {};

    stage(0, 0);
    stage(1, 1);
    vmwait<LPT>();                               // tile 0 resident, tile 1 in flight
    pipe_barrier();

    for (int t = 0; t < T; ++t) {
        if (t + 2 < T) stage((t + 2) % 3, t + 2);
        const u16* sA = mybuf + (t % 3) * BUFSZ;
        const u16* sB = sA + ATILE;

        f16x8 a[FR], b[4];
#pragma unroll
        for (int i = 0; i < FR; ++i) a[i] = *(const f16x8*)&sA[(wr + i * 16 + lr) * 32 + kg * 8];
#pragma unroll
        for (int i = 0; i < 4; ++i)  b[i] = *(const f16x8*)&sB[(wc + i * 16 + lr) * 32 + kg * 8];
#pragma unroll
        for (int mi = 0; mi < FR; ++mi)
#pragma unroll
            for (int ni = 0; ni < 4; ++ni)
                acc[mi][ni] = __builtin_amdgcn_mfma_f32_16x16x32_f16(a[mi], b[ni], acc[mi][ni], 0, 0, 0);

        if (t + 2 < T) vmwait<LPT>();            // tile t+1 resident, t+2 in flight
        else           vmwait<0>();              // drain before wrap/epilogue
        pipe_barrier();
    }

    if constexpr (SPLITK == 2) {
        // reduce high-half partials into low-half acc via LDS (reuse staging LDS)
        float* red = (float*)smem;
        const int slot = (wl * 64 + l) * (FR * 4);
        if (kw == 1) {
#pragma unroll
            for (int mi = 0; mi < FR; ++mi)
#pragma unroll
                for (int ni = 0; ni < 4; ++ni)
                    *(f32x4*)&red[(slot + mi * 4 + ni) * 4] = acc[mi][ni];
        }
        __syncthreads();
        if (kw == 1) return;
#pragma unroll
        for (int mi = 0; mi < FR; ++mi)
#pragma unroll
            for (int ni = 0; ni < 4; ++ni)
                acc[mi][ni] += *(const f32x4*)&red[(slot + mi * 4 + ni) * 4];
    }

#pragma unroll
    for (int mi = 0; mi < FR; ++mi) {
        const int mbase = m0 + wr + mi * 16 + kg * 4;
#pragma unroll
        for (int ni = 0; ni < 4; ++ni) {
            const int n = n0 + wc + ni * 16 + lr;
            const float bv = bias ? bias[n] : 0.0f;
            if constexpr (OMODE == 3) {
                const int bb = mbase >> 11;
                const int s  = mbase & 2047;
                u16x4 o;
#pragma unroll
                for (int j = 0; j < 4; ++j) o[j] = f2h_bits(acc[mi][ni][j] + bv);
                *(u16x4*)((u16*)C + ((size_t)bb * 512 + n) * 2048 + s) = o;
            } else {
#pragma unroll
                for (int j = 0; j < 4; ++j) {
                    float x = acc[mi][ni][j] + bv;
                    if constexpr (RELU) x = fmaxf(x, 0.0f);
                    const size_t idx = (size_t)(mbase + j) * ldc + n;
                    if constexpr (OMODE == 0) C[idx] = x;
                    else                      ((u16*)C)[idx] = f2h_bits(x);
                }
            }
        }
    }
}

// Row softmax over [rows][2048] fp32 -> fp16 probabilities.
__global__ __launch_bounds__(256)
void softmax_rows(const float* __restrict__ S, u16* __restrict__ P) {
    const int row = blockIdx.x;
    const float* s = S + (size_t)row * 2048;
    u16* p = P + (size_t)row * 2048;
    const int t = threadIdx.x;
    const int l = t & 63, w = t >> 6;

    f32x4 v0 = *(const f32x4*)&s[t * 8];
    f32x4 v1 = *(const f32x4*)&s[t * 8 + 4];
    float m = v0[0];
#pragma unroll
    for (int j = 1; j < 4; ++j) m = fmaxf(m, v0[j]);
#pragma unroll
    for (int j = 0; j < 4; ++j) m = fmaxf(m, v1[j]);
#pragma unroll
    for (int off = 1; off < 64; off <<= 1) m = fmaxf(m, __shfl_xor(m, off));

    __shared__ float redm[4], reds[4];
    if (l == 0) redm[w] = m;
    __syncthreads();
    m = fmaxf(fmaxf(redm[0], redm[1]), fmaxf(redm[2], redm[3]));

    float e[8]; float sum = 0.0f;
#pragma unroll
    for (int j = 0; j < 4; ++j) { e[j]     = __expf(v0[j] - m); sum += e[j]; }
#pragma unroll
    for (int j = 0; j < 4; ++j) { e[4 + j] = __expf(v1[j] - m); sum += e[4 + j]; }
#pragma unroll
    for (int off = 1; off < 64; off <<= 1) sum += __shfl_xor(sum, off);
    if (l == 0) reds[w] = sum;
    __syncthreads();
    sum = reds[0] + reds[1] + reds[2] + reds[3];
    const float inv = 1.0f / sum;

    u16x4 o0, o1;
#pragma unroll
    for (int j = 0; j < 4; ++j) { o0[j] = f2h_bits(e[j] * inv); o1[j] = f2h_bits(e[4 + j] * inv); }
    *(u16x4*)&p[t * 8]     = o0;
    *(u16x4*)&p[t * 8 + 4] = o1;
}

extern "C" void kernel_launch(void* const* d_in, const int* in_sizes, int n_in,
                              void* d_out, int out_size, void* d_ws, size_t ws_size,
                              hipStream_t stream) {
    const float* x  = (const float*)d_in[0];
    const float* Wq = (const float*)d_in[1];
    const float* bq = (const float*)d_in[2];
    const float* Wk = (const float*)d_in[3];
    const float* bk = (const float*)d_in[4];
    const float* Wv = (const float*)d_in[5];
    const float* bv = (const float*)d_in[6];
    const float* W1 = (const float*)d_in[7];
    const float* b1 = (const float*)d_in[8];
    const float* W2 = (const float*)d_in[9];
    const float* b2 = (const float*)d_in[10];
    float* out = (float*)d_out;

    char* ws = (char*)d_ws;
    size_t off = 0;
    auto alloc = [&](size_t bytes) { void* p = ws + off; off += (bytes + 255) & ~(size_t)255; return p; };
    u16* x16    = (u16*)alloc(8192ull * 512 * 2);       //  8.4 MB fp16
    u16* Wqk16  = (u16*)alloc(1024ull * 512 * 2);       //  Wq rows 0-511, Wk rows 512-1023
    u16* Wv16   = (u16*)alloc(512ull * 512 * 2);
    u16* W116   = (u16*)alloc(2048ull * 512 * 2);
    u16* W216   = (u16*)alloc(512ull * 2048 * 2);
    float* bqk  = (float*)alloc(1024 * 4);
    u16* pbuf   = (u16*)alloc(4ull * 2048 * 2048 * 2);  // 33.6 MB: qk lives here first, then P
    u16* vt     = (u16*)alloc(4ull * 512 * 2048 * 2);   //  8.4 MB fp16 [b][d][s]
    float* scores = (float*)alloc(4ull * 2048 * 2048 * 4); // 67.1 MB
    u16* qk   = pbuf;                   // fp16 [8192][1024]: q cols 0-511, k cols 512-1023
    u16* P    = pbuf;                   // fp16 [4][2048][2048]; qk dead after scores GEMM
    u16* attn = x16;                    // fp16 [8192][512]; x dead after projections
    u16* h    = (u16*)scores;           // fp16 [8192][2048]; scores dead after softmax
    if (ws_size < off) return;          // scratch too small: fail validation loudly

    dim3 blk(256), blk2(512);

    // one-time operand conversion (1 dispatch)
    cvt_all<<<dim3(6913), blk, 0, stream>>>(x, Wq, Wk, Wv, W1, W2, bq, bk,
                                            x16, Wqk16, Wv16, W116, W216, bqk);

    // qk = x @ [Wq;Wk]^T + [bq;bk]   (fp16 out)              1024 blocks
    gemm16<64, 1, false, 2, u16><<<dim3(16, 64, 1), blk, 0, stream>>>(
        x16, Wqk16, bqk, qk, 512, 512, 512, 1024, 0, 0, 0);
    // vt[b][d][s] = (x @ Wv^T + bv)^T                         512 blocks, splitK=2
    gemm16<64, 2, false, 3, u16><<<dim3(8, 64, 1), blk2, 0, stream>>>(
        x16, Wv16, bv, vt, 512, 512, 512, 0, 0, 0, 0);
    // scores[b] = q[b] @ k[b]^T   (fp32 out)                  1024 blocks
    gemm16<128, 1, false, 0, float><<<dim3(16, 16, 4), blk, 0, stream>>>(
        qk, qk + 512, nullptr, scores, 512, 1024, 1024, 2048,
        2048L * 1024, 2048L * 1024, 2048L * 2048);
    // P = softmax(scores) -> fp16 (overwrites dead qk region)
    softmax_rows<<<dim3(8192), blk, 0, stream>>>(scores, P);
    // attn[b] = P[b] @ V[b]   (fp16 out)                      512 blocks, splitK=2
    gemm16<64, 2, false, 2, u16><<<dim3(8, 16, 4), blk2, 0, stream>>>(
        P, vt, nullptr, attn, 2048, 2048, 2048, 512,
        2048L * 2048, 512L * 2048, 2048L * 512);
    // h = relu(attn @ W1^T + b1)   (fp16 out)                 1024 blocks
    gemm16<128, 1, true, 2, u16><<<dim3(16, 64, 1), blk, 0, stream>>>(
        attn, W116, b1, h, 512, 512, 512, 2048, 0, 0, 0);
    // out = h @ W2^T + b2   (fp32 out)                        512 blocks, splitK=2
    gemm16<64, 2, false, 0, float><<<dim3(8, 64, 1), blk2, 0, stream>>>(
        h, W216, b2, out, 2048, 2048, 2048, 512, 0, 0, 0);
}

// Round 8
// 185.974 us; speedup vs baseline: 1.0468x; 1.0468x over previous
//
#include <hip/hip_runtime.h>
#include <hip/hip_bf16.h>

typedef _Float16  f16x8  __attribute__((ext_vector_type(8)));
typedef float     f32x4  __attribute__((ext_vector_type(4)));
typedef unsigned short u16;
typedef u16       u16x4  __attribute__((ext_vector_type(4)));
typedef u16       u16x8  __attribute__((ext_vector_type(8)));

__device__ __forceinline__ u16 f2h_bits(float f) {
    union { _Float16 h; u16 u; } v; v.h = (_Float16)f; return v.u;
}
__device__ __forceinline__ float h2f(u16 b) {
    union { u16 u; _Float16 h; } v; v.u = b; return (float)v.h;
}

// ALL fp32->fp16 conversions (x + Wq|Wk|Wv stacked + W1 + W2) + bias concat, ONE dispatch.
__global__ __launch_bounds__(256)
void cvt_all(const float* __restrict__ x,
             const float* __restrict__ Wq, const float* __restrict__ Wk,
             const float* __restrict__ Wv, const float* __restrict__ W1,
             const float* __restrict__ W2, const float* __restrict__ bq,
             const float* __restrict__ bk, const float* __restrict__ bv,
             u16* __restrict__ x16, u16* __restrict__ Wqkv16,
             u16* __restrict__ W116, u16* __restrict__ W216, float* __restrict__ bqkv) {
    const int i = blockIdx.x * 256 + threadIdx.x;
    constexpr int X4 = 8192 * 512 / 4;           // 1048576
    constexpr int S = 512 * 512 / 4, L = 2048 * 512 / 4;
    const float* src; u16* dst; int j;
    if      (i < X4)                 { src = x;  dst = x16;            j = i;                  }
    else if (i < X4 + S)             { src = Wq; dst = Wqkv16;         j = i - X4;             }
    else if (i < X4 + 2 * S)         { src = Wk; dst = Wqkv16 + 4 * S; j = i - X4 - S;         }
    else if (i < X4 + 3 * S)         { src = Wv; dst = Wqkv16 + 8 * S; j = i - X4 - 2 * S;     }
    else if (i < X4 + 3 * S + L)     { src = W1; dst = W116;           j = i - X4 - 3 * S;     }
    else if (i < X4 + 3 * S + 2 * L) { src = W2; dst = W216;           j = i - X4 - 3 * S - L; }
    else if (i < X4 + 3 * S + 2 * L + 384) {
        const int g = (i - X4 - 3 * S - 2 * L) * 4;
#pragma unroll
        for (int t = 0; t < 4; ++t) {
            const int e = g + t;
            bqkv[e] = (e < 512) ? bq[e] : (e < 1024 ? bk[e - 512] : bv[e - 1024]);
        }
        return;
    } else return;
    f32x4 v = ((const f32x4*)src)[j];
    u16x4 h;
#pragma unroll
    for (int t = 0; t < 4; ++t) h[t] = f2h_bits(v[t]);
    ((u16x4*)dst)[j] = h;
}

// Stage a ROWSx32 16-bit tile (row-major, ld elems) into linear LDS [ROWS][32] via
// global_load_lds dwordx4. 4 waves (wl in 0..3) cooperate.
template<int ROWS>
__device__ __forceinline__ void stage_rows(const u16* __restrict__ g0, int ld, u16* lds, int wl) {
    const int l = threadIdx.x & 63;
    constexpr int CH = ROWS / 64;
#pragma unroll
    for (int i = 0; i < CH; ++i) {
        const int base = (wl * CH + i) << 10;    // wave-uniform byte offset in tile
        const int off  = base + (l << 4);
        const int row  = off >> 6;               // 64 B per row (32 elems)
        const int cb   = off & 63;
        const u16* g = g0 + (size_t)row * ld + (cb >> 1);
        __builtin_amdgcn_global_load_lds((const __attribute__((address_space(1))) void*)g,
                                         (__attribute__((address_space(3))) void*)((char*)lds + base),
                                         16, 0, 0);
    }
}

// C[M,N] = A[M,K] @ B[N,K]^T (+bias). fp16 operands, fp32 accumulate.
// 2-slot double-buffer, stage-before-compute (verified round-6 schedule).
// SPLITK=2: 512 threads; waves 0-3 do K/2 low, 4-7 high (own dbuf), LDS-reduce.
// OMODE: 0 = fp32 out; 2 = fp16 out; 4 = fused QKV (qk fp16 linear n<1024, vt transposed n>=1024);
//        5 = shifted-fp16 scores out + per-(row,64col) max array (xtra).
template<int BN, int SPLITK, bool RELU, int OMODE, typename TC>
__global__ __launch_bounds__(256 * SPLITK, 4)
void gemm16(const u16* __restrict__ Ag, const u16* __restrict__ Bg,
            const float* __restrict__ bias, TC* __restrict__ C, void* __restrict__ xtra,
            int K, int lda, int ldb, int ldc,
            long sA, long sB, long sC)
{
    // XCD-aware bijective swizzle (all grids have nwg % 8 == 0).
    const int nx = gridDim.x, ny = gridDim.y;
    const int nwg = nx * ny * gridDim.z;
    int bid = blockIdx.x + nx * (blockIdx.y + ny * blockIdx.z);
    int swz = (bid & 7) * (nwg >> 3) + (bid >> 3);
    const int n0 = (swz % nx) * BN; swz /= nx;
    const int m0 = (swz % ny) * 128;
    const int bz = swz / ny;

    constexpr int FR = (BN == 128) ? 4 : 2;      // 16-row A-fragments per wave
    constexpr int ATILE = 128 * 32;
    constexpr int BTILE = BN * 32;
    constexpr int BUFSZ = ATILE + BTILE;
    __shared__ __align__(16) u16 smem[SPLITK * 2 * BUFSZ];

    const int l  = threadIdx.x & 63, w = threadIdx.x >> 6;
    const int kw = (SPLITK == 2) ? (w >> 2) : 0; // k-half id
    const int wl = w & 3;                        // wave id within half
    const int wr = (BN == 128) ? (wl >> 1) * 64 : wl * 32;
    const int wc = (BN == 128) ? (wl & 1) * 64 : 0;
    const int lr = l & 15, kg = l >> 4;

    const int Kh = K / SPLITK;
    const int kb = kw * Kh;

    const u16* Ab = Ag + (size_t)bz * sA + (size_t)m0 * lda + kb;
    const u16* Bb = Bg + (size_t)bz * sB + (size_t)n0 * ldb + kb;
    C += (size_t)bz * sC;

    u16* mybuf = smem + kw * 2 * BUFSZ;

    auto stage = [&](int buf, int k0) {
        u16* s = mybuf + buf * BUFSZ;
        stage_rows<128>(Ab + k0, lda, s, wl);
        stage_rows<BN>(Bb + k0, ldb, s + ATILE, wl);
    };

    f32x4 acc[FR][4] = {};

    stage(0, 0);
    __syncthreads();
    int cur = 0;
    for (int k0 = 0; k0 < Kh; k0 += 32) {
        if (k0 + 32 < Kh) stage(cur ^ 1, k0 + 32);   // prefetch next tile
        const u16* sA = mybuf + cur * BUFSZ;
        const u16* sB = sA + ATILE;

        f16x8 a[FR], b[4];
#pragma unroll
        for (int i = 0; i < FR; ++i) a[i] = *(const f16x8*)&sA[(wr + i * 16 + lr) * 32 + kg * 8];
#pragma unroll
        for (int i = 0; i < 4; ++i)  b[i] = *(const f16x8*)&sB[(wc + i * 16 + lr) * 32 + kg * 8];
#pragma unroll
        for (int mi = 0; mi < FR; ++mi)
#pragma unroll
            for (int ni = 0; ni < 4; ++ni)
                acc[mi][ni] = __builtin_amdgcn_mfma_f32_16x16x32_f16(a[mi], b[ni], acc[mi][ni], 0, 0, 0);
        __syncthreads();
        cur ^= 1;
    }

    if constexpr (SPLITK == 2) {
        float* red = (float*)smem;
        const int slot = (wl * 64 + l) * (FR * 4);
        if (kw == 1) {
#pragma unroll
            for (int mi = 0; mi < FR; ++mi)
#pragma unroll
                for (int ni = 0; ni < 4; ++ni)
                    *(f32x4*)&red[(slot + mi * 4 + ni) * 4] = acc[mi][ni];
        }
        __syncthreads();
        if (kw == 1) return;
#pragma unroll
        for (int mi = 0; mi < FR; ++mi)
#pragma unroll
            for (int ni = 0; ni < 4; ++ni)
                acc[mi][ni] += *(const f32x4*)&red[(slot + mi * 4 + ni) * 4];
    }

    if constexpr (OMODE == 5) {
        // scores: per-(row, 64-col block) max -> MB; store fp16 (s - max).
        float* MB = (float*)xtra + (size_t)bz * 2048 * 32;
        const int cb = (n0 + wc) >> 6;
#pragma unroll
        for (int mi = 0; mi < FR; ++mi) {
            const int mbase = m0 + wr + mi * 16 + kg * 4;
#pragma unroll
            for (int j = 0; j < 4; ++j) {
                float rmax = fmaxf(fmaxf(acc[mi][0][j], acc[mi][1][j]),
                                   fmaxf(acc[mi][2][j], acc[mi][3][j]));
                rmax = fmaxf(rmax, __shfl_xor(rmax, 1));
                rmax = fmaxf(rmax, __shfl_xor(rmax, 2));
                rmax = fmaxf(rmax, __shfl_xor(rmax, 4));
                rmax = fmaxf(rmax, __shfl_xor(rmax, 8));
                const int row = mbase + j;
                if ((l & 15) == 0) MB[(size_t)row * 32 + cb] = rmax;
#pragma unroll
                for (int ni = 0; ni < 4; ++ni)
                    ((u16*)C)[(size_t)row * ldc + (n0 + wc + ni * 16 + lr)] =
                        f2h_bits(acc[mi][ni][j] - rmax);
            }
        }
        return;
    }

#pragma unroll
    for (int mi = 0; mi < FR; ++mi) {
        const int mbase = m0 + wr + mi * 16 + kg * 4;
#pragma unroll
        for (int ni = 0; ni < 4; ++ni) {
            const int n = n0 + wc + ni * 16 + lr;
            const float bv = bias ? bias[n] : 0.0f;
            if constexpr (OMODE == 4) {
                if (n0 < 1024) {        // q|k region, fp16 linear [8192][1024]
#pragma unroll
                    for (int j = 0; j < 4; ++j)
                        ((u16*)C)[(size_t)(mbase + j) * ldc + n] = f2h_bits(acc[mi][ni][j] + bv);
                } else {                // v region, transposed vt[4][512][2048]
                    const int d  = n - 1024;
                    const int bb = mbase >> 11;
                    const int s  = mbase & 2047;
                    u16x4 o;
#pragma unroll
                    for (int j = 0; j < 4; ++j) o[j] = f2h_bits(acc[mi][ni][j] + bv);
                    *(u16x4*)((u16*)xtra + ((size_t)bb * 512 + d) * 2048 + s) = o;
                }
            } else {
#pragma unroll
                for (int j = 0; j < 4; ++j) {
                    float x = acc[mi][ni][j] + bv;
                    if constexpr (RELU) x = fmaxf(x, 0.0f);
                    const size_t idx = (size_t)(mbase + j) * ldc + n;
                    if constexpr (OMODE == 0) C[idx] = x;
                    else                      ((u16*)C)[idx] = f2h_bits(x);
                }
            }
        }
    }
}

// Row softmax over [rows][2048] shifted-fp16 scores (+ per-64col fp32 base) -> fp16 P.
__global__ __launch_bounds__(256)
void softmax_rows(const u16* __restrict__ S16, const float* __restrict__ MB, u16* __restrict__ P) {
    const int row = blockIdx.x;
    const u16* s = S16 + (size_t)row * 2048;
    u16* p = P + (size_t)row * 2048;
    const int t = threadIdx.x;
    const int l = t & 63, w = t >> 6;
    const float base = MB[(size_t)row * 32 + (t >> 3)];

    u16x8 hv = *(const u16x8*)&s[t * 8];
    float v[8];
#pragma unroll
    for (int j = 0; j < 8; ++j) v[j] = h2f(hv[j]) + base;

    float m = v[0];
#pragma unroll
    for (int j = 1; j < 8; ++j) m = fmaxf(m, v[j]);
#pragma unroll
    for (int off = 1; off < 64; off <<= 1) m = fmaxf(m, __shfl_xor(m, off));

    __shared__ float redm[4], reds[4];
    if (l == 0) redm[w] = m;
    __syncthreads();
    m = fmaxf(fmaxf(redm[0], redm[1]), fmaxf(redm[2], redm[3]));

    float e[8]; float sum = 0.0f;
#pragma unroll
    for (int j = 0; j < 8; ++j) { e[j] = __expf(v[j] - m); sum += e[j]; }
#pragma unroll
    for (int off = 1; off < 64; off <<= 1) sum += __shfl_xor(sum, off);
    if (l == 0) reds[w] = sum;
    __syncthreads();
    sum = reds[0] + reds[1] + reds[2] + reds[3];
    const float inv = 1.0f / sum;

    u16x4 o0, o1;
#pragma unroll
    for (int j = 0; j < 4; ++j) { o0[j] = f2h_bits(e[j] * inv); o1[j] = f2h_bits(e[4 + j] * inv); }
    *(u16x4*)&p[t * 8]     = o0;
    *(u16x4*)&p[t * 8 + 4] = o1;
}

extern "C" void kernel_launch(void* const* d_in, const int* in_sizes, int n_in,
                              void* d_out, int out_size, void* d_ws, size_t ws_size,
                              hipStream_t stream) {
    const float* x  = (const float*)d_in[0];
    const float* Wq = (const float*)d_in[1];
    const float* bq = (const float*)d_in[2];
    const float* Wk = (const float*)d_in[3];
    const float* bk = (const float*)d_in[4];
    const float* Wv = (const float*)d_in[5];
    const float* bv = (const float*)d_in[6];
    const float* W1 = (const float*)d_in[7];
    const float* b1 = (const float*)d_in[8];
    const float* W2 = (const float*)d_in[9];
    const float* b2 = (const float*)d_in[10];
    float* out = (float*)d_out;

    char* ws = (char*)d_ws;
    size_t off = 0;
    auto alloc = [&](size_t bytes) { void* p = ws + off; off += (bytes + 255) & ~(size_t)255; return p; };
    u16* x16    = (u16*)alloc(8192ull * 512 * 2);        //  8.4 MB; attn overlays later
    u16* Wqkv16 = (u16*)alloc(1536ull * 512 * 2);        //  Wq rows 0-511, Wk 512-1023, Wv 1024-1535
    u16* W116   = (u16*)alloc(2048ull * 512 * 2);
    u16* W216   = (u16*)alloc(512ull * 2048 * 2);
    float* bqkv = (float*)alloc(1536 * 4);
    u16* pbuf   = (u16*)alloc(4ull * 2048 * 2048 * 2);   // 33.6 MB: qk first, then P
    u16* s16    = (u16*)alloc(4ull * 2048 * 2048 * 2);   // 33.6 MB: shifted-fp16 scores, then h
    u16* vt     = (u16*)alloc(4ull * 512 * 2048 * 2);    //  8.4 MB fp16 [b][d][s]
    float* mb   = (float*)alloc(8192ull * 32 * 4);       //  1.0 MB per-(row,64col) score max
    u16* qk   = pbuf;                   // fp16 [8192][1024]
    u16* P    = pbuf;                   // fp16 [4][2048][2048]; qk dead after scores GEMM
    u16* attn = x16;                    // fp16 [8192][512]; x dead after projections
    u16* h    = s16;                    // fp16 [8192][2048]; scores dead after softmax
    if (ws_size < off) return;          // scratch too small: fail validation loudly

    dim3 blk(256), blk2(512);

    // one-time operand conversion (1 dispatch)
    cvt_all<<<dim3(6914), blk, 0, stream>>>(x, Wq, Wk, Wv, W1, W2, bq, bk, bv,
                                            x16, Wqkv16, W116, W216, bqkv);

    // [q|k|vt] = x @ [Wq;Wk;Wv]^T + b   (fused, 1536 blocks)
    gemm16<64, 1, false, 4, u16><<<dim3(24, 64, 1), blk, 0, stream>>>(
        x16, Wqkv16, bqkv, qk, vt, 512, 512, 512, 1024, 0, 0, 0);
    // scores[b] = q[b] @ k[b]^T  -> shifted fp16 + mb        1024 blocks
    gemm16<128, 1, false, 5, u16><<<dim3(16, 16, 4), blk, 0, stream>>>(
        qk, qk + 512, nullptr, s16, mb, 512, 1024, 1024, 2048,
        2048L * 1024, 2048L * 1024, 2048L * 2048);
    // P = softmax(scores) -> fp16 (overwrites dead qk region)
    softmax_rows<<<dim3(8192), blk, 0, stream>>>(s16, mb, P);
    // attn[b] = P[b] @ V[b]   (fp16 out)                      512 blocks, splitK=2
    gemm16<64, 2, false, 2, u16><<<dim3(8, 16, 4), blk2, 0, stream>>>(
        P, vt, nullptr, attn, nullptr, 2048, 2048, 2048, 512,
        2048L * 2048, 512L * 2048, 2048L * 512);
    // h = relu(attn @ W1^T + b1)   (fp16 out, overlays s16)   1024 blocks
    gemm16<128, 1, true, 2, u16><<<dim3(16, 64, 1), blk, 0, stream>>>(
        attn, W116, b1, h, nullptr, 512, 512, 512, 2048, 0, 0, 0);
    // out = h @ W2^T + b2   (fp32 out)                        512 blocks, splitK=2
    gemm16<64, 2, false, 0, float><<<dim3(8, 64, 1), blk2, 0, stream>>>(
        h, W216, b2, out, nullptr, 2048, 2048, 2048, 512, 0, 0, 0);
}